// Round 1
// 197.422 us; speedup vs baseline: 1.0876x; 1.0876x over previous
//
#include <hip/hip_runtime.h>

typedef __attribute__((ext_vector_type(8))) short short8;
typedef __attribute__((ext_vector_type(4))) float f32x4;
typedef unsigned short u16;
typedef unsigned int u32;

// b=16, C=256, n=4096(64x64), HEADS=4, D=32, hidden=128
// y = G[b] . x + b_out  with  G[b] = W_out . C_bd[b] . W_q   (q never materialized)

__device__ __forceinline__ u16 f2bf(float f) {
    u32 x = __float_as_uint(f);
    u32 r = (x + 0x7fffu + ((x >> 16) & 1u)) >> 16;
    return (u16)r;
}
__device__ __forceinline__ float bf2f(u16 h) {
    return __uint_as_float(((u32)h) << 16);
}

typedef __attribute__((address_space(1))) u32 as1_u32;
typedef __attribute__((address_space(3))) u32 as3_u32;
__device__ __forceinline__ void gload16(const void* g, void* l) {
    // async 16B global -> LDS (dest = wave-uniform base + lane*16; our LDS offsets are t*16-linear)
    __builtin_amdgcn_global_load_lds((as1_u32*)g, (as3_u32*)l, 16, 0, 0);
}

// ---------------- K-1: convert W_qkv fp32 -> bf16 (all 384 rows; only rows 128..383 used by GEMM) ----
__global__ __launch_bounds__(256) void k_convW(const float* __restrict__ W,
                                               u16* __restrict__ Wb) {
    int idx = blockIdx.x * 256 + threadIdx.x;   // 98304/4 = 24576 threads
    float4 v = *reinterpret_cast<const float4*>(W + idx * 4);
    u32 w0 = (u32)f2bf(v.x) | ((u32)f2bf(v.y) << 16);
    u32 w1 = (u32)f2bf(v.z) | ((u32)f2bf(v.w) << 16);
    uint2 o = {w0, w1};
    *reinterpret_cast<uint2*>(Wb + idx * 4) = o;
}

// ---------------- K0: transpose x[b][c][n] (fp32) -> xT[b][n][c] (bf16) ----------------
__global__ __launch_bounds__(256) void k_transpose(const float* __restrict__ x,
                                                   u16* __restrict__ xT) {
    __shared__ alignas(16) u16 tile[64 * 72];
    int t = threadIdx.x;
    int n0 = blockIdx.x * 64, c0 = blockIdx.y * 64, b = blockIdx.z;
    int rr = t >> 4, nq = (t & 15) * 4;
#pragma unroll
    for (int i = 0; i < 4; i++) {
        int cl = i * 16 + rr;
        float4 v = *reinterpret_cast<const float4*>(x + ((size_t)(b * 256 + c0 + cl) * 4096 + n0 + nq));
        u32 w0 = (u32)f2bf(v.x) | ((u32)f2bf(v.y) << 16);
        u32 w1 = (u32)f2bf(v.z) | ((u32)f2bf(v.w) << 16);
        uint2 o = {w0, w1};
        *reinterpret_cast<uint2*>(&tile[cl * 72 + nq]) = o;
    }
    __syncthreads();
    int r = t >> 3, c8 = (t & 7) * 8;
#pragma unroll
    for (int i = 0; i < 2; i++) {
        int nl = i * 32 + r;
        alignas(16) u16 vals[8];
#pragma unroll
        for (int j = 0; j < 8; j++) vals[j] = tile[(c8 + j) * 72 + nl];
        *reinterpret_cast<uint4*>(xT + ((size_t)(b * 4096 + n0 + nl) * 256 + c0 + c8)) =
            *reinterpret_cast<const uint4*>(vals);
    }
}

// ---------------- K1: kv GEMM, 128x128 tile, global_load_lds staging (m97-style) ----------------
// grid (mt=2, nt=32, b=16); mt=0 -> k (W rows 128..255), mt=1 -> v (rows 256..383)
__global__ __launch_bounds__(256) void k_kv(const u16* __restrict__ xT,
                                            const u16* __restrict__ W,
                                            u16* __restrict__ kb,
                                            u16* __restrict__ vb) {
    __shared__ alignas(16) u16 sA[128 * 64];
    __shared__ alignas(16) u16 sB[128 * 64];
    int t = threadIdx.x;
    int mt = blockIdx.x, n0 = blockIdx.y * 128, b = blockIdx.z;
    int m0 = 128 + mt * 128;
    int lane = t & 63, wv = t >> 6, l16 = lane & 15, lq = lane >> 4;
    int wr = wv >> 1, wc = wv & 1;
    int trow = t >> 3, tc8 = (t & 7) * 8;

    f32x4 acc[4][4];
#pragma unroll
    for (int i = 0; i < 4; i++)
#pragma unroll
        for (int j = 0; j < 4; j++) acc[i][j] = (f32x4){0.f, 0.f, 0.f, 0.f};

    const u16* Asrc = W + (size_t)m0 * 256;
    const u16* Bsrc = xT + (size_t)(b * 4096 + n0) * 256;

    for (int kc = 0; kc < 4; kc++) {
        __syncthreads();
#pragma unroll
        for (int q = 0; q < 4; q++) {
            int row = q * 32 + trow;
            // LDS byte offset = q*4096 + t*16 -> linear in t (global_load_lds requirement)
            gload16(Asrc + (size_t)row * 256 + kc * 64 + tc8, &sA[row * 64 + tc8]);
            gload16(Bsrc + (size_t)row * 256 + kc * 64 + tc8, &sB[row * 64 + tc8]);
        }
        __syncthreads();   // drains vmcnt (compiler-inserted) before fragment reads
#pragma unroll
        for (int ks = 0; ks < 2; ks++) {
            int col = ks * 32 + lq * 8;
            short8 af[4], bfr[4];
#pragma unroll
            for (int i = 0; i < 4; i++)
                af[i] = *reinterpret_cast<const short8*>(&sA[(wr * 64 + i * 16 + l16) * 64 + col]);
#pragma unroll
            for (int j = 0; j < 4; j++)
                bfr[j] = *reinterpret_cast<const short8*>(&sB[(wc * 64 + j * 16 + l16) * 64 + col]);
#pragma unroll
            for (int i = 0; i < 4; i++)
#pragma unroll
                for (int j = 0; j < 4; j++)
                    acc[i][j] = __builtin_amdgcn_mfma_f32_16x16x32_bf16(af[i], bfr[j], acc[i][j], 0, 0, 0);
        }
    }
    u16* dst = (mt == 0) ? kb : vb;
#pragma unroll
    for (int i = 0; i < 4; i++) {
        int obase = wr * 64 + i * 16 + lq * 4;
#pragma unroll
        for (int j = 0; j < 4; j++) {
            int n = n0 + wc * 64 + j * 16 + l16;
            f32x4 a = acc[i][j];
#pragma unroll
            for (int rr = 0; rr < 4; rr++)
                dst[(size_t)(b * 128 + obase + rr) * 4096 + n] = f2bf(a[rr]);
        }
    }
}

// ---------------- K2: ctx with inline exp (no max needed; |k|<~2) + denominator partials ---------
// num[bh][s][d][e] = sum_n exp(k[d][n]) v[e][n] over n-slice; den[bh][s][d] = sum_n exp(k[d][n])
__global__ __launch_bounds__(256) void k_ctx(const u16* __restrict__ kb,
                                             const u16* __restrict__ vb,
                                             float* __restrict__ part,
                                             float* __restrict__ denp) {
    __shared__ float sred[4][32][32];
    __shared__ float dls[4][32];
    int s = blockIdx.x, h = blockIdx.y, b = blockIdx.z;
    int t = threadIdx.x;
    int lane = t & 63, wv = t >> 6, l16 = lane & 15, lq = lane >> 4;
    int bh = b * 4 + h;
    const u16* Kb = kb + (size_t)(b * 128 + h * 32) * 4096;
    const u16* Vb = vb + (size_t)(b * 128 + h * 32) * 4096;
    int nb = s * 512 + wv * 128;

    f32x4 acc[2][2];
#pragma unroll
    for (int i = 0; i < 2; i++)
#pragma unroll
        for (int j = 0; j < 2; j++) acc[i][j] = (f32x4){0.f, 0.f, 0.f, 0.f};
    float s0 = 0.f, s1 = 0.f;

#pragma unroll
    for (int kk = 0; kk < 4; kk++) {
        int col = nb + kk * 32 + lq * 8;
        short8 af[2], bfr[2];
#pragma unroll
        for (int i = 0; i < 2; i++) {
            short8 raw = *reinterpret_cast<const short8*>(Kb + (size_t)(i * 16 + l16) * 4096 + col);
            short8 pf;
            float ssum = 0.f;
#pragma unroll
            for (int e = 0; e < 8; e++) {
                float ef = __expf(bf2f((u16)raw[e]));
                ssum += ef;
                pf[e] = (short)f2bf(ef);
            }
            if (i == 0) s0 += ssum; else s1 += ssum;
            af[i] = pf;
        }
#pragma unroll
        for (int j = 0; j < 2; j++)
            bfr[j] = *reinterpret_cast<const short8*>(Vb + (size_t)(j * 16 + l16) * 4096 + col);
#pragma unroll
        for (int i = 0; i < 2; i++)
#pragma unroll
            for (int j = 0; j < 2; j++)
                acc[i][j] = __builtin_amdgcn_mfma_f32_16x16x32_bf16(af[i], bfr[j], acc[i][j], 0, 0, 0);
    }
    // row-sum reduce across the 4 lq column-groups (lanes +-16, +-32)
    s0 += __shfl_xor(s0, 16, 64); s0 += __shfl_xor(s0, 32, 64);
    s1 += __shfl_xor(s1, 16, 64); s1 += __shfl_xor(s1, 32, 64);
    if (lane < 16) { dls[wv][l16] = s0; dls[wv][16 + l16] = s1; }
    // D[d][e]: row=lq*4+rr -> d, col=l16 -> e
#pragma unroll
    for (int i = 0; i < 2; i++)
#pragma unroll
        for (int j = 0; j < 2; j++)
#pragma unroll
            for (int rr = 0; rr < 4; rr++)
                sred[wv][i * 16 + lq * 4 + rr][j * 16 + l16] = acc[i][j][rr];
    __syncthreads();
    if (t < 32) {
        float d = dls[0][t] + dls[1][t] + dls[2][t] + dls[3][t];
        denp[(size_t)(bh * 8 + s) * 32 + t] = d;
    }
    int de0 = t * 4;
    const float* p0 = &sred[0][0][0];
    f32x4 sum;
#pragma unroll
    for (int q = 0; q < 4; q++)
        sum[q] = p0[de0 + q] + p0[1024 + de0 + q] + p0[2048 + de0 + q] + p0[3072 + de0 + q];
    *reinterpret_cast<f32x4*>(part + (size_t)(bh * 8 + s) * 1024 + de0) = sum;
}

// ---------------- K3: reduce partials, divide by den -> C[bh][d][e] fp32 ----------------
__global__ __launch_bounds__(256) void k_red(const float* __restrict__ part,
                                             const float* __restrict__ denp,
                                             float* __restrict__ C) {
    __shared__ float invd[32];
    int bh = blockIdx.x, t = threadIdx.x;
    if (t < 32) {
        float d = 0.f;
#pragma unroll
        for (int s = 0; s < 8; s++) d += denp[(size_t)(bh * 8 + s) * 32 + t];
        invd[t] = 1.0f / d;
    }
    __syncthreads();
    int de0 = t * 4;
    float a0 = 0.f, a1 = 0.f, a2 = 0.f, a3 = 0.f;
#pragma unroll
    for (int s = 0; s < 8; s++) {
        f32x4 v = *reinterpret_cast<const f32x4*>(part + (size_t)(bh * 8 + s) * 1024 + de0);
        a0 += v[0]; a1 += v[1]; a2 += v[2]; a3 += v[3];
    }
    float iv = invd[de0 >> 5];
    f32x4 o = {a0 * iv, a1 * iv, a2 * iv, a3 * iv};
    *reinterpret_cast<f32x4*>(C + (size_t)bh * 1024 + de0) = o;
}

// ---------------- K4: G[b] = W_out . C_bd[b] . W_q  (fp32 VALU) -> bf16 ----------------
// grid (b=16, ot=16): 16 o-rows per block, all 256 c columns.
__global__ __launch_bounds__(256) void k_G(const float* __restrict__ C,
                                           const float* __restrict__ Wout,
                                           const float* __restrict__ Wqkv,   // rows 0..127 = W_q
                                           u16* __restrict__ Gb) {
    __shared__ float Cs[4096];    // [h][d][e]
    __shared__ float Us[2048];    // [ol][he], ol<16, he<128
    int b = blockIdx.x, ot = blockIdx.y, t = threadIdx.x;
    int o0 = ot * 16;
#pragma unroll
    for (int q = 0; q < 16; q++) {
        int idx = q * 256 + t;
        Cs[idx] = C[(size_t)b * 4096 + idx];
    }
    __syncthreads();
    // U[ol][he] = sum_d Wout[o0+ol][h*32+d] * C[h][d][e]   (he = h*32+e)
#pragma unroll
    for (int q = 0; q < 8; q++) {
        int idx = q * 256 + t;          // idx = ol*128 + he
        int ol = idx >> 7, he = idx & 127;
        int h = he >> 5, e = he & 31;
        const float* wrow = Wout + (o0 + ol) * 128 + h * 32;
        const float* crow = &Cs[h * 1024 + e];
        float a = 0.f;
#pragma unroll
        for (int d = 0; d < 32; d++) a += wrow[d] * crow[d * 32];
        Us[idx] = a;
    }
    __syncthreads();
    // G[o][c] = sum_he U[o][he] * Wq[he][c]
    int ol = t >> 4, c0 = (t & 15) * 16;
    float acc[16];
#pragma unroll
    for (int cc = 0; cc < 16; cc++) acc[cc] = 0.f;
    const float* Ur = &Us[ol * 128];
#pragma unroll 4
    for (int he = 0; he < 128; he++) {
        float u = Ur[he];
        const float4* wq = reinterpret_cast<const float4*>(Wqkv + he * 256 + c0);
#pragma unroll
        for (int q4 = 0; q4 < 4; q4++) {
            float4 w = wq[q4];
            acc[q4 * 4 + 0] += u * w.x;
            acc[q4 * 4 + 1] += u * w.y;
            acc[q4 * 4 + 2] += u * w.z;
            acc[q4 * 4 + 3] += u * w.w;
        }
    }
    alignas(16) u16 ob[16];
#pragma unroll
    for (int cc = 0; cc < 16; cc++) ob[cc] = f2bf(acc[cc]);
    u16* dst = Gb + (size_t)(b * 256 + o0 + ol) * 256 + c0;
    *reinterpret_cast<uint4*>(dst) = *reinterpret_cast<const uint4*>(ob);
    *reinterpret_cast<uint4*>(dst + 8) = *reinterpret_cast<const uint4*>(ob + 8);
}

// ---------------- K5: y = G[b] . x + bias, 128x128 tile, K=256, global_load_lds staging ----------
__global__ __launch_bounds__(256) void k_y(const u16* __restrict__ Gb,
                                           const u16* __restrict__ xT,
                                           const float* __restrict__ bout,
                                           float* __restrict__ y) {
    __shared__ alignas(16) u16 sA[128 * 64];
    __shared__ alignas(16) u16 sB[128 * 64];
    int t = threadIdx.x;
    int mt = blockIdx.x, n0 = blockIdx.y * 128, b = blockIdx.z;
    int m0 = mt * 128;
    int lane = t & 63, wv = t >> 6, l16 = lane & 15, lq = lane >> 4;
    int wr = wv >> 1, wc = wv & 1;
    int trow = t >> 3, tc8 = (t & 7) * 8;

    f32x4 acc[4][4];
#pragma unroll
    for (int i = 0; i < 4; i++)
#pragma unroll
        for (int j = 0; j < 4; j++) acc[i][j] = (f32x4){0.f, 0.f, 0.f, 0.f};

    const u16* Asrc = Gb + (size_t)(b * 256 + m0) * 256;
    const u16* Bsrc = xT + (size_t)(b * 4096 + n0) * 256;

    for (int kc = 0; kc < 4; kc++) {
        __syncthreads();
#pragma unroll
        for (int q = 0; q < 4; q++) {
            int row = q * 32 + trow;
            gload16(Asrc + (size_t)row * 256 + kc * 64 + tc8, &sA[row * 64 + tc8]);
            gload16(Bsrc + (size_t)row * 256 + kc * 64 + tc8, &sB[row * 64 + tc8]);
        }
        __syncthreads();
#pragma unroll
        for (int ks = 0; ks < 2; ks++) {
            int col = ks * 32 + lq * 8;
            short8 af[4], bfr[4];
#pragma unroll
            for (int i = 0; i < 4; i++)
                af[i] = *reinterpret_cast<const short8*>(&sA[(wr * 64 + i * 16 + l16) * 64 + col]);
#pragma unroll
            for (int j = 0; j < 4; j++)
                bfr[j] = *reinterpret_cast<const short8*>(&sB[(wc * 64 + j * 16 + l16) * 64 + col]);
#pragma unroll
            for (int i = 0; i < 4; i++)
#pragma unroll
                for (int j = 0; j < 4; j++)
                    acc[i][j] = __builtin_amdgcn_mfma_f32_16x16x32_bf16(af[i], bfr[j], acc[i][j], 0, 0, 0);
        }
    }
#pragma unroll
    for (int i = 0; i < 4; i++) {
        int obase = m0 + wr * 64 + i * 16 + lq * 4;
#pragma unroll
        for (int j = 0; j < 4; j++) {
            int n = n0 + wc * 64 + j * 16 + l16;
#pragma unroll
            for (int rr = 0; rr < 4; rr++) {
                int o = obase + rr;
                y[(size_t)(b * 256 + o) * 4096 + n] = acc[i][j][rr] + bout[o];
            }
        }
    }
}

extern "C" void kernel_launch(void* const* d_in, const int* in_sizes, int n_in,
                              void* d_out, int out_size, void* d_ws, size_t ws_size,
                              hipStream_t stream) {
    const float* x    = (const float*)d_in[0];
    const float* Wqkv = (const float*)d_in[1];
    const float* Wout = (const float*)d_in[2];
    const float* bout = (const float*)d_in[3];
    float* y = (float*)d_out;

    // k/v (bf16, 16 MB each) borrow d_out; both dead before k_y writes y (stream-ordered).
    u16* kb = (u16*)d_out;
    u16* vb = (u16*)d_out + 8388608;

    char* ws = (char*)d_ws;
    u16*   xT   = (u16*)(ws);                     // 32 MB   [b][n][c] bf16, lives until k_y
    float* part = (float*)(ws + 33554432);        // 2 MB    num partials [bh][s][d*32+e]
    float* denp = (float*)(ws + 35651584);        // 64 KB   den partials [bh][s][d]
    float* C    = (float*)(ws + 35717120);        // 256 KB  [bh][d][e] fp32
    u16*   Gb   = (u16*)(ws + 35979264);          // 2 MB    [b][256][256] bf16
    u16*   Wb   = (u16*)(ws + 38076416);          // 192 KB  W_qkv bf16

    k_convW    <<<96, 256, 0, stream>>>(Wqkv, Wb);
    k_transpose<<<dim3(64, 4, 16), 256, 0, stream>>>(x, xT);
    k_kv       <<<dim3(2, 32, 16), 256, 0, stream>>>(xT, Wb, kb, vb);
    k_ctx      <<<dim3(8, 4, 16), 256, 0, stream>>>(kb, vb, part, denp);
    k_red      <<<64, 256, 0, stream>>>(part, denp, C);
    k_G        <<<dim3(16, 16), 256, 0, stream>>>(C, Wout, Wqkv, Gb);
    k_y        <<<dim3(2, 32, 16), 256, 0, stream>>>(Gb, xT, bout, y);
}

// Round 2
// 193.543 us; speedup vs baseline: 1.1094x; 1.0200x over previous
//
#include <hip/hip_runtime.h>

typedef __attribute__((ext_vector_type(8))) short short8;
typedef __attribute__((ext_vector_type(4))) float f32x4;
typedef unsigned short u16;
typedef unsigned int u32;

// b=16, C=256, n=4096(64x64), HEADS=4, D=32, hidden=128
// y = G[b] . x + b_out  with  G[b] = W_out . C_bd[b] . W_q
// k,v never materialized: kv-GEMM + exp + ctx fused in one kernel.

__device__ __forceinline__ u16 f2bf(float f) {
    u32 x = __float_as_uint(f);
    u32 r = (x + 0x7fffu + ((x >> 16) & 1u)) >> 16;
    return (u16)r;
}

typedef __attribute__((address_space(1))) u32 as1_u32;
typedef __attribute__((address_space(3))) u32 as3_u32;
__device__ __forceinline__ void gload16(const void* g, void* l) {
    __builtin_amdgcn_global_load_lds((as1_u32*)g, (as3_u32*)l, 16, 0, 0);
}

// ---------------- K1: fused transpose + kv GEMM + exp/den + ctx partials + xT writeout ----------
// grid (nt=32, b=16), 512 threads (8 waves). BM=256 (all k,v rows), BN=128, K=256.
__global__ __launch_bounds__(512) void k_fused(const float* __restrict__ x,
                                               const float* __restrict__ Wqkv,
                                               u16* __restrict__ xT,
                                               float* __restrict__ part,
                                               float* __restrict__ denp) {
    __shared__ alignas(16) char smem[104448];
    u16* sB = (u16*)smem;                   // [128 n][264 c]  (col-block XOR-swizzled)
    u16* sA = (u16*)(smem + 67584);         // [256 m][72]     (per-kc chunk)
    u16* Pl = (u16*)smem;                   // overlay: [128][136] exp(k) bf16
    u16* Vl = (u16*)(smem + 34816);         // overlay: [128][136] v bf16
    float* dpart = (float*)(smem + 69632);  // [128][2] den partials

    int t = threadIdx.x;
    int nt = blockIdx.x, b = blockIdx.y;
    int n0 = nt * 128;
    int lane = t & 63, wv = t >> 6, l16 = lane & 15, lq = lane >> 4;
    int wr = wv >> 1, wc = wv & 1;

    // ---- phase 1: x[c][n-slab] fp32 -> sB[n][c] bf16 (transposed, swizzled) ----
    for (int i = 0; i < 16; i++) {
        int qi = i * 512 + t;              // 0..8191
        int cl = qi >> 5;                  // 0..255
        int nq = (qi & 31) * 4;            // 0..124
        float4 v = *reinterpret_cast<const float4*>(x + ((size_t)(b * 256 + cl) * 4096 + n0 + nq));
        float vv[4] = {v.x, v.y, v.z, v.w};
#pragma unroll
        for (int j = 0; j < 4; j++) {
            int n = nq + j;
            int cs = cl ^ (((n >> 3) & 7) << 3);
            sB[n * 264 + cs] = f2bf(vv[j]);
        }
    }
    __syncthreads();
    // ---- phase 1b: xT tile writeout (coalesced; stores drain under the GEMM) ----
    for (int i = 0; i < 8; i++) {
        int wi = i * 512 + t;              // 0..4095
        int nl = wi >> 5;                  // 0..127
        int cg = (wi & 31) * 8;            // 0..248
        int cs = cg ^ (((nl >> 3) & 7) << 3);
        uint4 vals = *reinterpret_cast<const uint4*>(&sB[nl * 264 + cs]);
        *reinterpret_cast<uint4*>(xT + ((size_t)(b * 4096 + n0 + nl) * 256 + cg)) = vals;
    }

    // ---- main GEMM: A = W rows 128..383 (fp32 -> bf16 on the fly), B = sB ----
    f32x4 acc[4][4];
#pragma unroll
    for (int i = 0; i < 4; i++)
#pragma unroll
        for (int j = 0; j < 4; j++) acc[i][j] = (f32x4){0.f, 0.f, 0.f, 0.f};

    const float* Wsrc = Wqkv + 128 * 256;   // skip q rows
    for (int kc = 0; kc < 4; kc++) {
        __syncthreads();
#pragma unroll
        for (int q = 0; q < 8; q++) {
            int fi = q * 512 + t;          // 0..4095
            int row = fi >> 4, cq = (fi & 15) * 4;
            float4 w = *reinterpret_cast<const float4*>(Wsrc + (size_t)row * 256 + kc * 64 + cq);
            u32 w0 = (u32)f2bf(w.x) | ((u32)f2bf(w.y) << 16);
            u32 w1 = (u32)f2bf(w.z) | ((u32)f2bf(w.w) << 16);
            uint2 o = {w0, w1};
            *reinterpret_cast<uint2*>(&sA[row * 72 + cq]) = o;
        }
        __syncthreads();
#pragma unroll
        for (int ks = 0; ks < 2; ks++) {
            int colA = ks * 32 + lq * 8;
            int colB = kc * 64 + ks * 32 + lq * 8;
            short8 af[4], bfr[4];
#pragma unroll
            for (int i = 0; i < 4; i++)
                af[i] = *reinterpret_cast<const short8*>(&sA[(wr * 64 + i * 16 + l16) * 72 + colA]);
#pragma unroll
            for (int j = 0; j < 4; j++) {
                int n = wc * 64 + j * 16 + l16;
                int cs = colB ^ (((n >> 3) & 7) << 3);
                bfr[j] = *reinterpret_cast<const short8*>(&sB[n * 264 + cs]);
            }
#pragma unroll
            for (int i = 0; i < 4; i++)
#pragma unroll
                for (int j = 0; j < 4; j++)
                    acc[i][j] = __builtin_amdgcn_mfma_f32_16x16x32_bf16(af[i], bfr[j], acc[i][j], 0, 0, 0);
        }
    }
    __syncthreads();   // all sA/sB reads done; safe to overlay

    // ---- epilogue: P = exp(k) -> Pl, den partials; V -> Vl ----
    if (wr < 2) {
#pragma unroll
        for (int i = 0; i < 4; i++) {
            int rbase = wr * 64 + i * 16 + lq * 4;
            float srow[4] = {0.f, 0.f, 0.f, 0.f};
#pragma unroll
            for (int j = 0; j < 4; j++) {
                int n = wc * 64 + j * 16 + l16;
#pragma unroll
                for (int rr = 0; rr < 4; rr++) {
                    float e = __expf(acc[i][j][rr]);
                    Pl[(rbase + rr) * 136 + n] = f2bf(e);
                    srow[rr] += e;
                }
            }
#pragma unroll
            for (int rr = 0; rr < 4; rr++) {
                float s = srow[rr];
                s += __shfl_xor(s, 1, 64); s += __shfl_xor(s, 2, 64);
                s += __shfl_xor(s, 4, 64); s += __shfl_xor(s, 8, 64);
                if (l16 == 0) dpart[(rbase + rr) * 2 + wc] = s;
            }
        }
    } else {
#pragma unroll
        for (int i = 0; i < 4; i++) {
            int rbase = (wr - 2) * 64 + i * 16 + lq * 4;
#pragma unroll
            for (int j = 0; j < 4; j++) {
                int n = wc * 64 + j * 16 + l16;
#pragma unroll
                for (int rr = 0; rr < 4; rr++)
                    Vl[(rbase + rr) * 136 + n] = f2bf(acc[i][j][rr]);
            }
        }
    }
    __syncthreads();

    // ---- ctx GEMM: per head h: C_part[d][e] = sum_n P[h*32+d][n] * V[h*32+e][n] (K=128) ----
    int h = wv >> 1, eh = wv & 1;
    f32x4 a2[2];
    a2[0] = (f32x4){0.f, 0.f, 0.f, 0.f};
    a2[1] = (f32x4){0.f, 0.f, 0.f, 0.f};
#pragma unroll
    for (int kk = 0; kk < 4; kk++) {
        int col = kk * 32 + lq * 8;
        short8 bfr = *reinterpret_cast<const short8*>(&Vl[(h * 32 + eh * 16 + l16) * 136 + col]);
#pragma unroll
        for (int i = 0; i < 2; i++) {
            short8 af = *reinterpret_cast<const short8*>(&Pl[(h * 32 + i * 16 + l16) * 136 + col]);
            a2[i] = __builtin_amdgcn_mfma_f32_16x16x32_bf16(af, bfr, a2[i], 0, 0, 0);
        }
    }
    float* pp = part + ((size_t)(b * 32 + nt) * 4 + h) * 1024;
#pragma unroll
    for (int i = 0; i < 2; i++)
#pragma unroll
        for (int rr = 0; rr < 4; rr++)
            pp[(i * 16 + lq * 4 + rr) * 32 + eh * 16 + l16] = a2[i][rr];

    if (t < 128)
        denp[((size_t)b * 128 + t) * 32 + nt] = dpart[t * 2] + dpart[t * 2 + 1];
}

// ---------------- K2: reduce 32 ctx partials + divide by den -> C[bh][d][e] fp32 ----------------
__global__ __launch_bounds__(256) void k_red(const float* __restrict__ part,
                                             const float* __restrict__ denp,
                                             float* __restrict__ C) {
    __shared__ float invd[32];
    int bh = blockIdx.x;
    int b = bh >> 2, h = bh & 3;
    int t = threadIdx.x;
    if (t < 32) {
        const float* dp = denp + ((size_t)b * 128 + h * 32 + t) * 32;
        float s = 0.f;
#pragma unroll
        for (int nt = 0; nt < 32; nt++) s += dp[nt];
        invd[t] = 1.0f / s;
    }
    __syncthreads();
    int de0 = t * 4;
    float a0 = 0.f, a1 = 0.f, a2 = 0.f, a3 = 0.f;
#pragma unroll 8
    for (int nt = 0; nt < 32; nt++) {
        f32x4 v = *reinterpret_cast<const f32x4*>(part + ((size_t)(b * 32 + nt) * 4 + h) * 1024 + de0);
        a0 += v[0]; a1 += v[1]; a2 += v[2]; a3 += v[3];
    }
    float iv = invd[de0 >> 5];
    f32x4 o = {a0 * iv, a1 * iv, a2 * iv, a3 * iv};
    *reinterpret_cast<f32x4*>(C + (size_t)bh * 1024 + de0) = o;
}

// ---------------- K3: G[b] = W_out . C_bd[b] . W_q  (fp32 VALU) -> bf16 ----------------
__global__ __launch_bounds__(256) void k_G(const float* __restrict__ C,
                                           const float* __restrict__ Wout,
                                           const float* __restrict__ Wqkv,   // rows 0..127 = W_q
                                           u16* __restrict__ Gb) {
    __shared__ float Cs[4096];    // [h][d][e]
    __shared__ float Us[2048];    // [ol][he]
    int b = blockIdx.x, ot = blockIdx.y, t = threadIdx.x;
    int o0 = ot * 16;
#pragma unroll
    for (int q = 0; q < 16; q++) {
        int idx = q * 256 + t;
        Cs[idx] = C[(size_t)b * 4096 + idx];
    }
    __syncthreads();
#pragma unroll
    for (int q = 0; q < 8; q++) {
        int idx = q * 256 + t;          // ol*128 + he
        int ol = idx >> 7, he = idx & 127;
        int h = he >> 5, e = he & 31;
        const float* wrow = Wout + (o0 + ol) * 128 + h * 32;
        const float* crow = &Cs[h * 1024 + e];
        float a = 0.f;
#pragma unroll
        for (int d = 0; d < 32; d++) a += wrow[d] * crow[d * 32];
        Us[idx] = a;
    }
    __syncthreads();
    int ol = t >> 4, c0 = (t & 15) * 16;
    float acc[16];
#pragma unroll
    for (int cc = 0; cc < 16; cc++) acc[cc] = 0.f;
    const float* Ur = &Us[ol * 128];
#pragma unroll 4
    for (int he = 0; he < 128; he++) {
        float u = Ur[he];
        const float4* wq = reinterpret_cast<const float4*>(Wqkv + he * 256 + c0);
#pragma unroll
        for (int q4 = 0; q4 < 4; q4++) {
            float4 w = wq[q4];
            acc[q4 * 4 + 0] += u * w.x;
            acc[q4 * 4 + 1] += u * w.y;
            acc[q4 * 4 + 2] += u * w.z;
            acc[q4 * 4 + 3] += u * w.w;
        }
    }
    alignas(16) u16 ob[16];
#pragma unroll
    for (int cc = 0; cc < 16; cc++) ob[cc] = f2bf(acc[cc]);
    u16* dst = Gb + (size_t)(b * 256 + o0 + ol) * 256 + c0;
    *reinterpret_cast<uint4*>(dst) = *reinterpret_cast<const uint4*>(ob);
    *reinterpret_cast<uint4*>(dst + 8) = *reinterpret_cast<const uint4*>(ob + 8);
}

// ---------------- K4: y = G[b] . x + bias, 128x128 tile, K=256, global_load_lds staging ----------
__global__ __launch_bounds__(256) void k_y(const u16* __restrict__ Gb,
                                           const u16* __restrict__ xT,
                                           const float* __restrict__ bout,
                                           float* __restrict__ y) {
    __shared__ alignas(16) u16 sA[128 * 64];
    __shared__ alignas(16) u16 sB[128 * 64];
    int t = threadIdx.x;
    int mt = blockIdx.x, n0 = blockIdx.y * 128, b = blockIdx.z;
    int m0 = mt * 128;
    int lane = t & 63, wv = t >> 6, l16 = lane & 15, lq = lane >> 4;
    int wr = wv >> 1, wc = wv & 1;
    int trow = t >> 3, tc8 = (t & 7) * 8;

    f32x4 acc[4][4];
#pragma unroll
    for (int i = 0; i < 4; i++)
#pragma unroll
        for (int j = 0; j < 4; j++) acc[i][j] = (f32x4){0.f, 0.f, 0.f, 0.f};

    const u16* Asrc = Gb + (size_t)(b * 256 + m0) * 256;
    const u16* Bsrc = xT + (size_t)(b * 4096 + n0) * 256;

    for (int kc = 0; kc < 4; kc++) {
        __syncthreads();
#pragma unroll
        for (int q = 0; q < 4; q++) {
            int row = q * 32 + trow;
            gload16(Asrc + (size_t)row * 256 + kc * 64 + tc8, &sA[row * 64 + tc8]);
            gload16(Bsrc + (size_t)row * 256 + kc * 64 + tc8, &sB[row * 64 + tc8]);
        }
        __syncthreads();
#pragma unroll
        for (int ks = 0; ks < 2; ks++) {
            int col = ks * 32 + lq * 8;
            short8 af[4], bfr[4];
#pragma unroll
            for (int i = 0; i < 4; i++)
                af[i] = *reinterpret_cast<const short8*>(&sA[(wr * 64 + i * 16 + l16) * 64 + col]);
#pragma unroll
            for (int j = 0; j < 4; j++)
                bfr[j] = *reinterpret_cast<const short8*>(&sB[(wc * 64 + j * 16 + l16) * 64 + col]);
#pragma unroll
            for (int i = 0; i < 4; i++)
#pragma unroll
                for (int j = 0; j < 4; j++)
                    acc[i][j] = __builtin_amdgcn_mfma_f32_16x16x32_bf16(af[i], bfr[j], acc[i][j], 0, 0, 0);
        }
    }
#pragma unroll
    for (int i = 0; i < 4; i++) {
        int obase = m0 + wr * 64 + i * 16 + lq * 4;
#pragma unroll
        for (int j = 0; j < 4; j++) {
            int n = n0 + wc * 64 + j * 16 + l16;
#pragma unroll
            for (int rr = 0; rr < 4; rr++) {
                int o = obase + rr;
                y[(size_t)(b * 256 + o) * 4096 + n] = acc[i][j][rr] + bout[o];
            }
        }
    }
}

extern "C" void kernel_launch(void* const* d_in, const int* in_sizes, int n_in,
                              void* d_out, int out_size, void* d_ws, size_t ws_size,
                              hipStream_t stream) {
    const float* x    = (const float*)d_in[0];
    const float* Wqkv = (const float*)d_in[1];
    const float* Wout = (const float*)d_in[2];
    const float* bout = (const float*)d_in[3];
    float* y = (float*)d_out;

    char* ws = (char*)d_ws;
    u16*   xT   = (u16*)(ws);                     // 32 MB   [b][n][c] bf16
    float* part = (float*)(ws + 33554432);        // 8 MB    ctx partials [b][nt][h][1024]
    float* denp = (float*)(ws + 41943040);        // 256 KB  den partials [b*128+row][nt]
    float* C    = (float*)(ws + 42205184);        // 256 KB  [bh][d][e] fp32
    u16*   Gb   = (u16*)(ws + 42467328);          // 2 MB    [b][256][256] bf16

    k_fused<<<dim3(32, 16), 512, 0, stream>>>(x, Wqkv, xT, part, denp);
    k_red  <<<64, 256, 0, stream>>>(part, denp, C);
    k_G    <<<dim3(16, 16), 256, 0, stream>>>(C, Wout, Wqkv, Gb);
    k_y    <<<dim3(2, 32, 16), 256, 0, stream>>>(Gb, xT, bout, y);
}

// Round 3
// 174.953 us; speedup vs baseline: 1.2273x; 1.1063x over previous
//
#include <hip/hip_runtime.h>

typedef __attribute__((ext_vector_type(8))) short short8;
typedef __attribute__((ext_vector_type(4))) float f32x4;
typedef unsigned short u16;
typedef unsigned int u32;

// b=16, C=256, n=4096(64x64), HEADS=4, D=32, hidden=128
// y = G[b] . x + b_out  with  G[b] = W_out . C_bd[b] . W_q
// k,v never hit HBM: kv-GEMM + exp + ctx fused; transpose is a separate streaming kernel.

__device__ __forceinline__ u16 f2bf(float f) {
    u32 x = __float_as_uint(f);
    u32 r = (x + 0x7fffu + ((x >> 16) & 1u)) >> 16;
    return (u16)r;
}
__device__ __forceinline__ float bf2f(u16 h) {
    return __uint_as_float(((u32)h) << 16);
}

typedef __attribute__((address_space(1))) u32 as1_u32;
typedef __attribute__((address_space(3))) u32 as3_u32;
__device__ __forceinline__ void gload16(const void* g, void* l) {
    // async 16B global -> LDS (dest = wave-uniform base + lane*16)
    __builtin_amdgcn_global_load_lds((as1_u32*)g, (as3_u32*)l, 16, 0, 0);
}

// ---------------- K-1: convert W_qkv fp32 -> bf16 (rows 0..127 = W_q used by k_G; 128..383 by k_fused)
__global__ __launch_bounds__(256) void k_convW(const float* __restrict__ W,
                                               u16* __restrict__ Wb) {
    int idx = blockIdx.x * 256 + threadIdx.x;   // 98304/4 = 24576 threads
    float4 v = *reinterpret_cast<const float4*>(W + idx * 4);
    u32 w0 = (u32)f2bf(v.x) | ((u32)f2bf(v.y) << 16);
    u32 w1 = (u32)f2bf(v.z) | ((u32)f2bf(v.w) << 16);
    uint2 o = {w0, w1};
    *reinterpret_cast<uint2*>(Wb + idx * 4) = o;
}

// ---------------- K0: transpose x[b][c][n] (fp32) -> xT[b][n][c] (bf16) ----------------
__global__ __launch_bounds__(256) void k_transpose(const float* __restrict__ x,
                                                   u16* __restrict__ xT) {
    __shared__ alignas(16) u16 tile[64 * 72];
    int t = threadIdx.x;
    int n0 = blockIdx.x * 64, c0 = blockIdx.y * 64, b = blockIdx.z;
    int rr = t >> 4, nq = (t & 15) * 4;
#pragma unroll
    for (int i = 0; i < 4; i++) {
        int cl = i * 16 + rr;
        float4 v = *reinterpret_cast<const float4*>(x + ((size_t)(b * 256 + c0 + cl) * 4096 + n0 + nq));
        u32 w0 = (u32)f2bf(v.x) | ((u32)f2bf(v.y) << 16);
        u32 w1 = (u32)f2bf(v.z) | ((u32)f2bf(v.w) << 16);
        uint2 o = {w0, w1};
        *reinterpret_cast<uint2*>(&tile[cl * 72 + nq]) = o;
    }
    __syncthreads();
    int r = t >> 3, c8 = (t & 7) * 8;
#pragma unroll
    for (int i = 0; i < 2; i++) {
        int nl = i * 32 + r;
        alignas(16) u16 vals[8];
#pragma unroll
        for (int j = 0; j < 8; j++) vals[j] = tile[(c8 + j) * 72 + nl];
        *reinterpret_cast<uint4*>(xT + ((size_t)(b * 4096 + n0 + nl) * 256 + c0 + c8)) =
            *reinterpret_cast<const uint4*>(vals);
    }
}

// ---------------- K1: fused kv GEMM (BM=256,BN=128,K=256) + exp/den + ctx partials ----------
// grid (nt=32, b=16), 512 threads (8 waves). Both operands via global_load_lds. 2 blocks/CU.
__global__ __launch_bounds__(512, 4) void k_fused(const u16* __restrict__ xT,
                                                  const u16* __restrict__ Wb,
                                                  float* __restrict__ part,
                                                  float* __restrict__ denp) {
    __shared__ alignas(16) char smem[70656];
    u16* sA = (u16*)smem;                   // [256 m][64]  per-kc chunk (linear, gload16)
    u16* sB = (u16*)(smem + 32768);         // [128 n][64]  per-kc chunk (linear, gload16)
    u16* Pl = (u16*)smem;                   // overlay: [128][136] exp(k) bf16
    u16* Vl = (u16*)(smem + 34816);         // overlay: [128][136] v bf16
    float* dpart = (float*)(smem + 69632);  // [128][2] den partials

    int t = threadIdx.x;
    int nt = blockIdx.x, b = blockIdx.y;
    int n0 = nt * 128;
    int lane = t & 63, wv = t >> 6, l16 = lane & 15, lq = lane >> 4;
    int wr = wv >> 1, wc = wv & 1;
    int trow = t >> 3, tc8 = (t & 7) * 8;

    f32x4 acc[4][4];
#pragma unroll
    for (int i = 0; i < 4; i++)
#pragma unroll
        for (int j = 0; j < 4; j++) acc[i][j] = (f32x4){0.f, 0.f, 0.f, 0.f};

    const u16* Asrc = Wb + 128 * 256;       // k,v weight rows
    const u16* Bsrc = xT + (size_t)(b * 4096 + n0) * 256;

    for (int kc = 0; kc < 4; kc++) {
        __syncthreads();
#pragma unroll
        for (int q = 0; q < 4; q++) {       // A: 256 rows x 64 c, LDS off = q*8192 + t*16 (linear)
            int row = q * 64 + trow;
            gload16(Asrc + (size_t)row * 256 + kc * 64 + tc8, &sA[row * 64 + tc8]);
        }
#pragma unroll
        for (int q = 0; q < 2; q++) {       // B: 128 rows x 64 c
            int row = q * 64 + trow;
            gload16(Bsrc + (size_t)row * 256 + kc * 64 + tc8, &sB[row * 64 + tc8]);
        }
        __syncthreads();                    // drains vmcnt before fragment reads
#pragma unroll
        for (int ks = 0; ks < 2; ks++) {
            int col = ks * 32 + lq * 8;
            short8 af[4], bfr[4];
#pragma unroll
            for (int i = 0; i < 4; i++)
                af[i] = *reinterpret_cast<const short8*>(&sA[(wr * 64 + i * 16 + l16) * 64 + col]);
#pragma unroll
            for (int j = 0; j < 4; j++)
                bfr[j] = *reinterpret_cast<const short8*>(&sB[(wc * 64 + j * 16 + l16) * 64 + col]);
#pragma unroll
            for (int i = 0; i < 4; i++)
#pragma unroll
                for (int j = 0; j < 4; j++)
                    acc[i][j] = __builtin_amdgcn_mfma_f32_16x16x32_bf16(af[i], bfr[j], acc[i][j], 0, 0, 0);
        }
    }
    __syncthreads();   // all sA/sB reads done; safe to overlay

    // ---- epilogue: P = exp(k) -> Pl, den partials; V -> Vl (m rows 0..127 = k, 128..255 = v) ----
    if (wr < 2) {
#pragma unroll
        for (int i = 0; i < 4; i++) {
            int rbase = wr * 64 + i * 16 + lq * 4;
            float srow[4] = {0.f, 0.f, 0.f, 0.f};
#pragma unroll
            for (int j = 0; j < 4; j++) {
                int n = wc * 64 + j * 16 + l16;
#pragma unroll
                for (int rr = 0; rr < 4; rr++) {
                    float e = __expf(acc[i][j][rr]);
                    Pl[(rbase + rr) * 136 + n] = f2bf(e);
                    srow[rr] += e;
                }
            }
#pragma unroll
            for (int rr = 0; rr < 4; rr++) {
                float s = srow[rr];
                s += __shfl_xor(s, 1, 64); s += __shfl_xor(s, 2, 64);
                s += __shfl_xor(s, 4, 64); s += __shfl_xor(s, 8, 64);
                if (l16 == 0) dpart[(rbase + rr) * 2 + wc] = s;
            }
        }
    } else {
#pragma unroll
        for (int i = 0; i < 4; i++) {
            int rbase = (wr - 2) * 64 + i * 16 + lq * 4;
#pragma unroll
            for (int j = 0; j < 4; j++) {
                int n = wc * 64 + j * 16 + l16;
#pragma unroll
                for (int rr = 0; rr < 4; rr++)
                    Vl[(rbase + rr) * 136 + n] = f2bf(acc[i][j][rr]);
            }
        }
    }
    __syncthreads();

    // ---- ctx GEMM: per head h: C_part[d][e] = sum_n P[h*32+d][n] * V[h*32+e][n] (K=128) ----
    int h = wv >> 1, eh = wv & 1;
    f32x4 a2[2];
    a2[0] = (f32x4){0.f, 0.f, 0.f, 0.f};
    a2[1] = (f32x4){0.f, 0.f, 0.f, 0.f};
#pragma unroll
    for (int kk = 0; kk < 4; kk++) {
        int col = kk * 32 + lq * 8;
        short8 bfr = *reinterpret_cast<const short8*>(&Vl[(h * 32 + eh * 16 + l16) * 136 + col]);
#pragma unroll
        for (int i = 0; i < 2; i++) {
            short8 af = *reinterpret_cast<const short8*>(&Pl[(h * 32 + i * 16 + l16) * 136 + col]);
            a2[i] = __builtin_amdgcn_mfma_f32_16x16x32_bf16(af, bfr, a2[i], 0, 0, 0);
        }
    }
    float* pp = part + ((size_t)(b * 32 + nt) * 4 + h) * 1024;
#pragma unroll
    for (int i = 0; i < 2; i++)
#pragma unroll
        for (int rr = 0; rr < 4; rr++)
            pp[(i * 16 + lq * 4 + rr) * 32 + eh * 16 + l16] = a2[i][rr];

    if (t < 128)
        denp[((size_t)b * 128 + t) * 32 + nt] = dpart[t * 2] + dpart[t * 2 + 1];
}

// ---------------- K2: reduce 32 ctx partials + divide by den -> C[bh][d][e] fp32 ----------------
__global__ __launch_bounds__(256) void k_red(const float* __restrict__ part,
                                             const float* __restrict__ denp,
                                             float* __restrict__ C) {
    __shared__ float invd[32];
    int bh = blockIdx.x;
    int b = bh >> 2, h = bh & 3;
    int t = threadIdx.x;
    if (t < 32) {
        const float* dp = denp + ((size_t)b * 128 + h * 32 + t) * 32;
        float s = 0.f;
#pragma unroll
        for (int nt = 0; nt < 32; nt++) s += dp[nt];
        invd[t] = 1.0f / s;
    }
    __syncthreads();
    int de0 = t * 4;
    float a0 = 0.f, a1 = 0.f, a2 = 0.f, a3 = 0.f;
#pragma unroll 8
    for (int nt = 0; nt < 32; nt++) {
        f32x4 v = *reinterpret_cast<const f32x4*>(part + ((size_t)(b * 32 + nt) * 4 + h) * 1024 + de0);
        a0 += v[0]; a1 += v[1]; a2 += v[2]; a3 += v[3];
    }
    float iv = invd[de0 >> 5];
    f32x4 o = {a0 * iv, a1 * iv, a2 * iv, a3 * iv};
    *reinterpret_cast<f32x4*>(C + (size_t)bh * 1024 + de0) = o;
}

// ---------------- K3: G[b] = W_out . C_bd[b] . W_q  -> bf16 (W_q read as bf16 from Wb) --------
// grid (b=16, ot=16, ch=2): 16 o-rows per block, 128 c columns per block.
__global__ __launch_bounds__(256) void k_G(const float* __restrict__ C,
                                           const float* __restrict__ Wout,
                                           const u16* __restrict__ Wb,   // rows 0..127 = W_q bf16
                                           u16* __restrict__ Gb) {
    __shared__ float Cs[4096];    // [h][d][e]
    __shared__ float Us[2048];    // [ol][he]
    int b = blockIdx.x, ot = blockIdx.y, ch = blockIdx.z, t = threadIdx.x;
    int o0 = ot * 16;
#pragma unroll
    for (int q = 0; q < 16; q++) {
        int idx = q * 256 + t;
        Cs[idx] = C[(size_t)b * 4096 + idx];
    }
    __syncthreads();
#pragma unroll
    for (int q = 0; q < 8; q++) {
        int idx = q * 256 + t;          // ol*128 + he
        int ol = idx >> 7, he = idx & 127;
        int h = he >> 5, e = he & 31;
        const float* wrow = Wout + (o0 + ol) * 128 + h * 32;
        const float* crow = &Cs[h * 1024 + e];
        float a = 0.f;
#pragma unroll
        for (int d = 0; d < 32; d++) a += wrow[d] * crow[d * 32];
        Us[idx] = a;
    }
    __syncthreads();
    int ol = t >> 4, c0 = ch * 128 + (t & 15) * 8;
    float acc[8];
#pragma unroll
    for (int cc = 0; cc < 8; cc++) acc[cc] = 0.f;
    const float* Ur = &Us[ol * 128];
#pragma unroll 4
    for (int he = 0; he < 128; he++) {
        float u = Ur[he];
        short8 w8 = *reinterpret_cast<const short8*>(Wb + he * 256 + c0);
#pragma unroll
        for (int e = 0; e < 8; e++)
            acc[e] += u * bf2f((u16)w8[e]);
    }
    alignas(16) u16 ob[8];
#pragma unroll
    for (int cc = 0; cc < 8; cc++) ob[cc] = f2bf(acc[cc]);
    *reinterpret_cast<uint4*>(Gb + (size_t)(b * 256 + o0 + ol) * 256 + c0) =
        *reinterpret_cast<const uint4*>(ob);
}

// ---------------- K4: y = G[b] . x + bias, 128x128 tile, K=256, global_load_lds staging ----------
__global__ __launch_bounds__(256) void k_y(const u16* __restrict__ Gb,
                                           const u16* __restrict__ xT,
                                           const float* __restrict__ bout,
                                           float* __restrict__ y) {
    __shared__ alignas(16) u16 sA[128 * 64];
    __shared__ alignas(16) u16 sB[128 * 64];
    int t = threadIdx.x;
    int mt = blockIdx.x, n0 = blockIdx.y * 128, b = blockIdx.z;
    int m0 = mt * 128;
    int lane = t & 63, wv = t >> 6, l16 = lane & 15, lq = lane >> 4;
    int wr = wv >> 1, wc = wv & 1;
    int trow = t >> 3, tc8 = (t & 7) * 8;

    f32x4 acc[4][4];
#pragma unroll
    for (int i = 0; i < 4; i++)
#pragma unroll
        for (int j = 0; j < 4; j++) acc[i][j] = (f32x4){0.f, 0.f, 0.f, 0.f};

    const u16* Asrc = Gb + (size_t)(b * 256 + m0) * 256;
    const u16* Bsrc = xT + (size_t)(b * 4096 + n0) * 256;

    for (int kc = 0; kc < 4; kc++) {
        __syncthreads();
#pragma unroll
        for (int q = 0; q < 4; q++) {
            int row = q * 32 + trow;
            gload16(Asrc + (size_t)row * 256 + kc * 64 + tc8, &sA[row * 64 + tc8]);
            gload16(Bsrc + (size_t)row * 256 + kc * 64 + tc8, &sB[row * 64 + tc8]);
        }
        __syncthreads();
#pragma unroll
        for (int ks = 0; ks < 2; ks++) {
            int col = ks * 32 + lq * 8;
            short8 af[4], bfr[4];
#pragma unroll
            for (int i = 0; i < 4; i++)
                af[i] = *reinterpret_cast<const short8*>(&sA[(wr * 64 + i * 16 + l16) * 64 + col]);
#pragma unroll
            for (int j = 0; j < 4; j++)
                bfr[j] = *reinterpret_cast<const short8*>(&sB[(wc * 64 + j * 16 + l16) * 64 + col]);
#pragma unroll
            for (int i = 0; i < 4; i++)
#pragma unroll
                for (int j = 0; j < 4; j++)
                    acc[i][j] = __builtin_amdgcn_mfma_f32_16x16x32_bf16(af[i], bfr[j], acc[i][j], 0, 0, 0);
        }
    }
#pragma unroll
    for (int i = 0; i < 4; i++) {
        int obase = m0 + wr * 64 + i * 16 + lq * 4;
#pragma unroll
        for (int j = 0; j < 4; j++) {
            int n = n0 + wc * 64 + j * 16 + l16;
#pragma unroll
            for (int rr = 0; rr < 4; rr++) {
                int o = obase + rr;
                y[(size_t)(b * 256 + o) * 4096 + n] = acc[i][j][rr] + bout[o];
            }
        }
    }
}

extern "C" void kernel_launch(void* const* d_in, const int* in_sizes, int n_in,
                              void* d_out, int out_size, void* d_ws, size_t ws_size,
                              hipStream_t stream) {
    const float* x    = (const float*)d_in[0];
    const float* Wqkv = (const float*)d_in[1];
    const float* Wout = (const float*)d_in[2];
    const float* bout = (const float*)d_in[3];
    float* y = (float*)d_out;

    char* ws = (char*)d_ws;
    u16*   xT   = (u16*)(ws);                     // 32 MB   [b][n][c] bf16
    float* part = (float*)(ws + 33554432);        // 8 MB    ctx partials [b][nt][h][1024]
    float* denp = (float*)(ws + 41943040);        // 256 KB  den partials [b*128+row][nt]
    float* C    = (float*)(ws + 42205184);        // 256 KB  [bh][d][e] fp32
    u16*   Gb   = (u16*)(ws + 42467328);          // 2 MB    [b][256][256] bf16
    u16*   Wb   = (u16*)(ws + 44564480);          // 192 KB  W_qkv bf16 (all 384 rows)

    k_convW    <<<96, 256, 0, stream>>>(Wqkv, Wb);
    k_transpose<<<dim3(64, 4, 16), 256, 0, stream>>>(x, xT);
    k_fused    <<<dim3(32, 16), 512, 0, stream>>>(xT, Wb, part, denp);
    k_red      <<<64, 256, 0, stream>>>(part, denp, C);
    k_G        <<<dim3(16, 16, 2), 256, 0, stream>>>(C, Wout, Wb, Gb);
    k_y        <<<dim3(2, 32, 16), 256, 0, stream>>>(Gb, xT, bout, y);
}

// Round 4
// 171.415 us; speedup vs baseline: 1.2526x; 1.0206x over previous
//
#include <hip/hip_runtime.h>

typedef __attribute__((ext_vector_type(8))) short short8;
typedef __attribute__((ext_vector_type(4))) float f32x4;
typedef unsigned short u16;
typedef unsigned int u32;

// b=16, C=256, n=4096(64x64), HEADS=4, D=32, hidden=128
// y = G[b] . x + b_out  with  G[b] = W_out . C_bd[b] . W_q
// k,v never hit HBM: kv-GEMM + exp + ctx fused; transpose is a separate streaming kernel.

__device__ __forceinline__ u16 f2bf(float f) {
    u32 x = __float_as_uint(f);
    u32 r = (x + 0x7fffu + ((x >> 16) & 1u)) >> 16;
    return (u16)r;
}
__device__ __forceinline__ float bf2f(u16 h) {
    return __uint_as_float(((u32)h) << 16);
}

typedef __attribute__((address_space(1))) u32 as1_u32;
typedef __attribute__((address_space(3))) u32 as3_u32;
__device__ __forceinline__ void gload16(const void* g, void* l) {
    // async 16B global -> LDS (dest = wave-uniform base + lane*16)
    __builtin_amdgcn_global_load_lds((as1_u32*)g, (as3_u32*)l, 16, 0, 0);
}

// ---------------- K0: transpose x[b][c][n] fp32 -> xT[b][n][c] bf16;  + W conv folded in ------
__global__ __launch_bounds__(256) void k_transpose(const float* __restrict__ x,
                                                   u16* __restrict__ xT,
                                                   const float* __restrict__ W,
                                                   u16* __restrict__ Wb) {
    __shared__ alignas(16) u16 tile[64 * 72];
    int t = threadIdx.x;
    int n0 = blockIdx.x * 64, c0 = blockIdx.y * 64, b = blockIdx.z;

    // ---- folded W_qkv fp32 -> bf16 conversion (96 chunks of 1024 floats) ----
    int flat = (b * 4 + blockIdx.y) * 64 + blockIdx.x;
    if (flat < 96) {
        int idx = flat * 256 + t;
        float4 v = *reinterpret_cast<const float4*>(W + (size_t)idx * 4);
        u32 w0 = (u32)f2bf(v.x) | ((u32)f2bf(v.y) << 16);
        u32 w1 = (u32)f2bf(v.z) | ((u32)f2bf(v.w) << 16);
        uint2 o = {w0, w1};
        *reinterpret_cast<uint2*>(Wb + (size_t)idx * 4) = o;
    }

    int rr = t >> 4, nq = (t & 15) * 4;
#pragma unroll
    for (int i = 0; i < 4; i++) {
        int cl = i * 16 + rr;
        float4 v = *reinterpret_cast<const float4*>(x + ((size_t)(b * 256 + c0 + cl) * 4096 + n0 + nq));
        u32 w0 = (u32)f2bf(v.x) | ((u32)f2bf(v.y) << 16);
        u32 w1 = (u32)f2bf(v.z) | ((u32)f2bf(v.w) << 16);
        uint2 o = {w0, w1};
        *reinterpret_cast<uint2*>(&tile[cl * 72 + nq]) = o;
    }
    __syncthreads();
    int r = t >> 3, c8 = (t & 7) * 8;
#pragma unroll
    for (int i = 0; i < 2; i++) {
        int nl = i * 32 + r;
        alignas(16) u16 vals[8];
#pragma unroll
        for (int j = 0; j < 8; j++) vals[j] = tile[(c8 + j) * 72 + nl];
        *reinterpret_cast<uint4*>(xT + ((size_t)(b * 4096 + n0 + nl) * 256 + c0 + c8)) =
            *reinterpret_cast<const uint4*>(vals);
    }
}

// ---------------- K1: fused kv GEMM (BM=256,BN=128,K=256) + exp/den + ctx partials ----------
// grid (nt=32, b=16), 512 threads (8 waves). Both operands via global_load_lds. 2 blocks/CU.
__global__ __launch_bounds__(512, 4) void k_fused(const u16* __restrict__ xT,
                                                  const u16* __restrict__ Wb,
                                                  float* __restrict__ part,
                                                  float* __restrict__ denp) {
    __shared__ alignas(16) char smem[70656];
    u16* sA = (u16*)smem;                   // [256 m][64]  per-kc chunk (linear, gload16)
    u16* sB = (u16*)(smem + 32768);         // [128 n][64]  per-kc chunk (linear, gload16)
    u16* Pl = (u16*)smem;                   // overlay: [128][136] exp(k) bf16
    u16* Vl = (u16*)(smem + 34816);         // overlay: [128][136] v bf16
    float* dpart = (float*)(smem + 69632);  // [128][2] den partials

    int t = threadIdx.x;
    int nt = blockIdx.x, b = blockIdx.y;
    int n0 = nt * 128;
    int lane = t & 63, wv = t >> 6, l16 = lane & 15, lq = lane >> 4;
    int wr = wv >> 1, wc = wv & 1;
    int trow = t >> 3, tc8 = (t & 7) * 8;

    f32x4 acc[4][4];
#pragma unroll
    for (int i = 0; i < 4; i++)
#pragma unroll
        for (int j = 0; j < 4; j++) acc[i][j] = (f32x4){0.f, 0.f, 0.f, 0.f};

    const u16* Asrc = Wb + 128 * 256;       // k,v weight rows
    const u16* Bsrc = xT + (size_t)(b * 4096 + n0) * 256;

    for (int kc = 0; kc < 4; kc++) {
        __syncthreads();
#pragma unroll
        for (int q = 0; q < 4; q++) {       // A: 256 rows x 64 c, LDS off = q*8192 + t*16 (linear)
            int row = q * 64 + trow;
            gload16(Asrc + (size_t)row * 256 + kc * 64 + tc8, &sA[row * 64 + tc8]);
        }
#pragma unroll
        for (int q = 0; q < 2; q++) {       // B: 128 rows x 64 c
            int row = q * 64 + trow;
            gload16(Bsrc + (size_t)row * 256 + kc * 64 + tc8, &sB[row * 64 + tc8]);
        }
        __syncthreads();                    // drains vmcnt before fragment reads
#pragma unroll
        for (int ks = 0; ks < 2; ks++) {
            int col = ks * 32 + lq * 8;
            short8 af[4], bfr[4];
#pragma unroll
            for (int i = 0; i < 4; i++)
                af[i] = *reinterpret_cast<const short8*>(&sA[(wr * 64 + i * 16 + l16) * 64 + col]);
#pragma unroll
            for (int j = 0; j < 4; j++)
                bfr[j] = *reinterpret_cast<const short8*>(&sB[(wc * 64 + j * 16 + l16) * 64 + col]);
#pragma unroll
            for (int i = 0; i < 4; i++)
#pragma unroll
                for (int j = 0; j < 4; j++)
                    acc[i][j] = __builtin_amdgcn_mfma_f32_16x16x32_bf16(af[i], bfr[j], acc[i][j], 0, 0, 0);
        }
    }
    __syncthreads();   // all sA/sB reads done; safe to overlay

    // ---- epilogue: P = exp(k) -> Pl, den partials; V -> Vl (m rows 0..127 = k, 128..255 = v) ----
    if (wr < 2) {
#pragma unroll
        for (int i = 0; i < 4; i++) {
            int rbase = wr * 64 + i * 16 + lq * 4;
            float srow[4] = {0.f, 0.f, 0.f, 0.f};
#pragma unroll
            for (int j = 0; j < 4; j++) {
                int n = wc * 64 + j * 16 + l16;
#pragma unroll
                for (int rr = 0; rr < 4; rr++) {
                    float e = __expf(acc[i][j][rr]);
                    Pl[(rbase + rr) * 136 + n] = f2bf(e);
                    srow[rr] += e;
                }
            }
#pragma unroll
            for (int rr = 0; rr < 4; rr++) {
                float s = srow[rr];
                s += __shfl_xor(s, 1, 64); s += __shfl_xor(s, 2, 64);
                s += __shfl_xor(s, 4, 64); s += __shfl_xor(s, 8, 64);
                if (l16 == 0) dpart[(rbase + rr) * 2 + wc] = s;
            }
        }
    } else {
#pragma unroll
        for (int i = 0; i < 4; i++) {
            int rbase = (wr - 2) * 64 + i * 16 + lq * 4;
#pragma unroll
            for (int j = 0; j < 4; j++) {
                int n = wc * 64 + j * 16 + l16;
#pragma unroll
                for (int rr = 0; rr < 4; rr++)
                    Vl[(rbase + rr) * 136 + n] = f2bf(acc[i][j][rr]);
            }
        }
    }
    __syncthreads();

    // ---- ctx GEMM: per head h: C_part[d][e] = sum_n P[h*32+d][n] * V[h*32+e][n] (K=128) ----
    int h = wv >> 1, eh = wv & 1;
    f32x4 a2[2];
    a2[0] = (f32x4){0.f, 0.f, 0.f, 0.f};
    a2[1] = (f32x4){0.f, 0.f, 0.f, 0.f};
#pragma unroll
    for (int kk = 0; kk < 4; kk++) {
        int col = kk * 32 + lq * 8;
        short8 bfr = *reinterpret_cast<const short8*>(&Vl[(h * 32 + eh * 16 + l16) * 136 + col]);
#pragma unroll
        for (int i = 0; i < 2; i++) {
            short8 af = *reinterpret_cast<const short8*>(&Pl[(h * 32 + i * 16 + l16) * 136 + col]);
            a2[i] = __builtin_amdgcn_mfma_f32_16x16x32_bf16(af, bfr, a2[i], 0, 0, 0);
        }
    }
    float* pp = part + ((size_t)(b * 32 + nt) * 4 + h) * 1024;
#pragma unroll
    for (int i = 0; i < 2; i++)
#pragma unroll
        for (int rr = 0; rr < 4; rr++)
            pp[(i * 16 + lq * 4 + rr) * 32 + eh * 16 + l16] = a2[i][rr];

    if (t < 128)
        denp[((size_t)b * 128 + t) * 32 + nt] = dpart[t * 2] + dpart[t * 2 + 1];
}

// ---------------- K2: reduce 32 ctx partials + divide by den -> C[bh][d][e] fp32 ----------------
__global__ __launch_bounds__(256) void k_red(const float* __restrict__ part,
                                             const float* __restrict__ denp,
                                             float* __restrict__ C) {
    __shared__ float invd[32];
    int bh = blockIdx.x;
    int b = bh >> 2, h = bh & 3;
    int t = threadIdx.x;
    if (t < 32) {
        const float* dp = denp + ((size_t)b * 128 + h * 32 + t) * 32;
        float s = 0.f;
#pragma unroll
        for (int nt = 0; nt < 32; nt++) s += dp[nt];
        invd[t] = 1.0f / s;
    }
    __syncthreads();
    int de0 = t * 4;
    float a0 = 0.f, a1 = 0.f, a2 = 0.f, a3 = 0.f;
#pragma unroll 8
    for (int nt = 0; nt < 32; nt++) {
        f32x4 v = *reinterpret_cast<const f32x4*>(part + ((size_t)(b * 32 + nt) * 4 + h) * 1024 + de0);
        a0 += v[0]; a1 += v[1]; a2 += v[2]; a3 += v[3];
    }
    float iv = invd[de0 >> 5];
    f32x4 o = {a0 * iv, a1 * iv, a2 * iv, a3 * iv};
    *reinterpret_cast<f32x4*>(C + (size_t)bh * 1024 + de0) = o;
}

// ---------------- K3: G[b] = W_out . C_bd[b] . W_q  -> bf16 (W_q read as bf16 from Wb) --------
// grid (b=16, ot=16, ch=2): 16 o-rows per block, 128 c columns per block.
__global__ __launch_bounds__(256) void k_G(const float* __restrict__ C,
                                           const float* __restrict__ Wout,
                                           const u16* __restrict__ Wb,   // rows 0..127 = W_q bf16
                                           u16* __restrict__ Gb) {
    __shared__ float Cs[4096];    // [h][d][e]
    __shared__ float Us[2048];    // [ol][he]
    int b = blockIdx.x, ot = blockIdx.y, ch = blockIdx.z, t = threadIdx.x;
    int o0 = ot * 16;
#pragma unroll
    for (int q = 0; q < 16; q++) {
        int idx = q * 256 + t;
        Cs[idx] = C[(size_t)b * 4096 + idx];
    }
    __syncthreads();
#pragma unroll
    for (int q = 0; q < 8; q++) {
        int idx = q * 256 + t;          // ol*128 + he
        int ol = idx >> 7, he = idx & 127;
        int h = he >> 5, e = he & 31;
        const float* wrow = Wout + (o0 + ol) * 128 + h * 32;
        const float* crow = &Cs[h * 1024 + e];
        float a = 0.f;
#pragma unroll
        for (int d = 0; d < 32; d++) a += wrow[d] * crow[d * 32];
        Us[idx] = a;
    }
    __syncthreads();
    int ol = t >> 4, c0 = ch * 128 + (t & 15) * 8;
    float acc[8];
#pragma unroll
    for (int cc = 0; cc < 8; cc++) acc[cc] = 0.f;
    const float* Ur = &Us[ol * 128];
#pragma unroll 4
    for (int he = 0; he < 128; he++) {
        float u = Ur[he];
        short8 w8 = *reinterpret_cast<const short8*>(Wb + he * 256 + c0);
#pragma unroll
        for (int e = 0; e < 8; e++)
            acc[e] += u * bf2f((u16)w8[e]);
    }
    alignas(16) u16 ob[8];
#pragma unroll
    for (int cc = 0; cc < 8; cc++) ob[cc] = f2bf(acc[cc]);
    *reinterpret_cast<uint4*>(Gb + (size_t)(b * 256 + o0 + ol) * 256 + c0) =
        *reinterpret_cast<const uint4*>(ob);
}

// ---------------- K4: y = G[b].x + bias, BM=256 x BN=128, K=256, xT slab read ONCE ----------
// grid (nt=32, b=16), 512 threads (8 waves, 4M x 2N).
__global__ __launch_bounds__(512, 4) void k_y(const u16* __restrict__ Gb,
                                              const u16* __restrict__ xT,
                                              const float* __restrict__ bout,
                                              float* __restrict__ y) {
    __shared__ alignas(16) u16 sA[256 * 64];
    __shared__ alignas(16) u16 sB[128 * 64];
    int t = threadIdx.x;
    int nt = blockIdx.x, b = blockIdx.y;
    int n0 = nt * 128;
    int lane = t & 63, wv = t >> 6, l16 = lane & 15, lq = lane >> 4;
    int wr = wv >> 1, wc = wv & 1;
    int trow = t >> 3, tc8 = (t & 7) * 8;

    f32x4 acc[4][4];
#pragma unroll
    for (int i = 0; i < 4; i++)
#pragma unroll
        for (int j = 0; j < 4; j++) acc[i][j] = (f32x4){0.f, 0.f, 0.f, 0.f};

    const u16* Asrc = Gb + (size_t)b * 256 * 256;
    const u16* Bsrc = xT + (size_t)(b * 4096 + n0) * 256;

    for (int kc = 0; kc < 4; kc++) {
        __syncthreads();
#pragma unroll
        for (int q = 0; q < 4; q++) {       // A: 256 rows x 64 c (linear in t)
            int row = q * 64 + trow;
            gload16(Asrc + (size_t)row * 256 + kc * 64 + tc8, &sA[row * 64 + tc8]);
        }
#pragma unroll
        for (int q = 0; q < 2; q++) {       // B: 128 rows x 64 c
            int row = q * 64 + trow;
            gload16(Bsrc + (size_t)row * 256 + kc * 64 + tc8, &sB[row * 64 + tc8]);
        }
        __syncthreads();
#pragma unroll
        for (int ks = 0; ks < 2; ks++) {
            int col = ks * 32 + lq * 8;
            short8 af[4], bfr[4];
#pragma unroll
            for (int i = 0; i < 4; i++)
                af[i] = *reinterpret_cast<const short8*>(&sA[(wr * 64 + i * 16 + l16) * 64 + col]);
#pragma unroll
            for (int j = 0; j < 4; j++)
                bfr[j] = *reinterpret_cast<const short8*>(&sB[(wc * 64 + j * 16 + l16) * 64 + col]);
#pragma unroll
            for (int i = 0; i < 4; i++)
#pragma unroll
                for (int j = 0; j < 4; j++)
                    acc[i][j] = __builtin_amdgcn_mfma_f32_16x16x32_bf16(af[i], bfr[j], acc[i][j], 0, 0, 0);
        }
    }
#pragma unroll
    for (int i = 0; i < 4; i++) {
        int obase = wr * 64 + i * 16 + lq * 4;
#pragma unroll
        for (int j = 0; j < 4; j++) {
            int n = n0 + wc * 64 + j * 16 + l16;
#pragma unroll
            for (int rr = 0; rr < 4; rr++) {
                int o = obase + rr;
                y[(size_t)(b * 256 + o) * 4096 + n] = acc[i][j][rr] + bout[o];
            }
        }
    }
}

extern "C" void kernel_launch(void* const* d_in, const int* in_sizes, int n_in,
                              void* d_out, int out_size, void* d_ws, size_t ws_size,
                              hipStream_t stream) {
    const float* x    = (const float*)d_in[0];
    const float* Wqkv = (const float*)d_in[1];
    const float* Wout = (const float*)d_in[2];
    const float* bout = (const float*)d_in[3];
    float* y = (float*)d_out;

    char* ws = (char*)d_ws;
    u16*   xT   = (u16*)(ws);                     // 32 MB   [b][n][c] bf16
    float* part = (float*)(ws + 33554432);        // 8 MB    ctx partials [b][nt][h][1024]
    float* denp = (float*)(ws + 41943040);        // 256 KB  den partials [b*128+row][nt]
    float* C    = (float*)(ws + 42205184);        // 256 KB  [bh][d][e] fp32
    u16*   Gb   = (u16*)(ws + 42467328);          // 2 MB    [b][256][256] bf16
    u16*   Wb   = (u16*)(ws + 44564480);          // 192 KB  W_qkv bf16 (all 384 rows)

    k_transpose<<<dim3(64, 4, 16), 256, 0, stream>>>(x, xT, Wqkv, Wb);
    k_fused    <<<dim3(32, 16), 512, 0, stream>>>(xT, Wb, part, denp);
    k_red      <<<64, 256, 0, stream>>>(part, denp, C);
    k_G        <<<dim3(16, 16, 2), 256, 0, stream>>>(C, Wout, Wb, Gb);
    k_y        <<<dim3(32, 16), 512, 0, stream>>>(Gb, xT, bout, y);
}